// Round 4
// baseline (189.625 us; speedup 1.0000x reference)
//
#include <hip/hip_runtime.h>

#define IN 128
#define PD 64
#define C1 64
#define C2 128
#define ICC 12
#define NOBJ 32
#define PADW 66   // 64 + 1 halo each side

typedef __attribute__((ext_vector_type(8))) short bf16x8;
typedef __attribute__((ext_vector_type(4))) float f32x4;

static __device__ __forceinline__ unsigned short f2bf(float f) {
  unsigned u = __float_as_uint(f);
  return (unsigned short)((u + 0x7FFFu + ((u >> 16) & 1u)) >> 16);  // RNE
}

// ---------------------------------------------------------------------------
// K0: pack w2 (128,64,3,3) f32 -> wp[tap][oc][ic] bf16  (147 KB)
// ---------------------------------------------------------------------------
__global__ __launch_bounds__(256) void k0_pack_w(
    const float* __restrict__ w2, unsigned short* __restrict__ wp)
{
  int i = blockIdx.x * 256 + threadIdx.x;
  if (i < 9 * C2 * C1) {
    int tap = i / (C2 * C1);
    int rem = i - tap * (C2 * C1);
    int oc = rem >> 6, ic = rem & 63;
    wp[i] = f2bf(w2[(oc * C1 + ic) * 9 + tap]);
  }
}

// ---------------------------------------------------------------------------
// K1: conv1 (12->64) + ReLU + maxpool2x2, f32 math.
// 2-phase LDS staging (6 ics/phase, float4 writes -> conflict-free, 3 barriers
// total). Output: padded NHWC bf16 xpad[B][66][66][64] (border pre-zeroed).
// ---------------------------------------------------------------------------
__global__ __launch_bounds__(256) void k1_conv1_pool(
    const float* __restrict__ img, const float* __restrict__ w1,
    const float* __restrict__ b1, unsigned short* __restrict__ xpad)
{
  const int px  = threadIdx.x;            // 0..63 pooled col
  const int qy  = threadIdx.y;            // 0..3
  const int P   = blockIdx.x * 4;         // pooled row base
  const int ocb = blockIdx.y * 16;        // 0,16,32,48
  const int b   = blockIdx.z;             // 0..31
  const int t   = qy * 64 + px;           // 0..255

  __shared__ float tile[6][10][136];      // 32.6 KB; data cols 4..131

  // zero halo cols 3 and 132 (stage never touches them; both phases reuse)
  if (t < 120) {
    const int icl = t / 20, rem = t % 20;
    tile[icl][rem >> 1][(rem & 1) ? 132 : 3] = 0.f;
  }

  const float* imgb = img + (size_t)b * ICC * IN * IN;
  const int irow0 = 2 * P - 1;

  float acc[16][4];
#pragma unroll
  for (int j = 0; j < 16; ++j)
#pragma unroll
    for (int p = 0; p < 4; ++p) acc[j][p] = 0.f;

  for (int p = 0; p < 2; ++p) {
    if (p) __syncthreads();               // phase-1 reads done before overwrite
    // stage 6 ics: 6*10 rows x 32 float4 = 1920 slots over 256 threads
    for (int i = t; i < 1920; i += 256) {
      const int icl = i / 320;
      const int rem = i - icl * 320;
      const int r = rem >> 5, c4 = (rem & 31) << 2;
      const int gy = irow0 + r;
      float4 v = make_float4(0.f, 0.f, 0.f, 0.f);
      if (gy >= 0 && gy < IN)
        v = *reinterpret_cast<const float4*>(
            imgb + (size_t)(p * 6 + icl) * IN * IN + gy * IN + c4);
      *reinterpret_cast<float4*>(&tile[icl][r][4 + c4]) = v;  // contiguous
    }
    __syncthreads();

#pragma unroll
    for (int icl = 0; icl < 6; ++icl) {
      float xw[4][4];
#pragma unroll
      for (int r = 0; r < 4; ++r)
#pragma unroll
        for (int c = 0; c < 4; ++c)
          xw[r][c] = tile[icl][2 * qy + r][2 * px + 3 + c];  // stride-2: free

      const int ic = p * 6 + icl;
#pragma unroll
      for (int j = 0; j < 16; ++j) {
        const float* wpt = w1 + (size_t)(ocb + j) * (ICC * 9) + ic * 9;
#pragma unroll
        for (int kr = 0; kr < 3; ++kr) {
#pragma unroll
          for (int kc = 0; kc < 3; ++kc) {
            const float wv = wpt[kr * 3 + kc];
            acc[j][0] = fmaf(wv, xw[kr    ][kc    ], acc[j][0]);
            acc[j][1] = fmaf(wv, xw[kr    ][kc + 1], acc[j][1]);
            acc[j][2] = fmaf(wv, xw[kr + 1][kc    ], acc[j][2]);
            acc[j][3] = fmaf(wv, xw[kr + 1][kc + 1], acc[j][3]);
          }
        }
      }
    }
  }

  const int py = P + qy;
  unsigned int pk[8];
#pragma unroll
  for (int j = 0; j < 16; ++j) {
    float m = fmaxf(fmaxf(acc[j][0], acc[j][1]), fmaxf(acc[j][2], acc[j][3]));
    m = fmaxf(fmaf(m, 1.f / 255.f, b1[ocb + j]), 0.f);
    unsigned short h = f2bf(m);
    if (j & 1) pk[j >> 1] |= ((unsigned int)h) << 16;
    else       pk[j >> 1]  = h;
  }
  unsigned short* dst = xpad + ((((size_t)b * PADW + (py + 1)) * PADW) + (px + 1)) * C1 + ocb;
  reinterpret_cast<uint4*>(dst)[0] = make_uint4(pk[0], pk[1], pk[2], pk[3]);
  reinterpret_cast<uint4*>(dst)[1] = make_uint4(pk[4], pk[5], pk[6], pk[7]);
}

// ---------------------------------------------------------------------------
// K2: conv2 implicit GEMM via MFMA bf16 + bias/ReLU + per-block segment max.
// Block: 512 thr (8 waves = 4M x 2N), 16x16 spatial x 128 oc. X tile
// 18x18x64 bf16 in LDS; swizzle applied to GLOBAL source column so LDS
// writes are lane-contiguous (conflict-free) and frag reads are 2-way.
// Partial 32x128 max written to ws (no global atomics); k3 reduces.
// ---------------------------------------------------------------------------
__global__ __launch_bounds__(512, 2) void k2_mfma(
    const unsigned short* __restrict__ xpad, const unsigned short* __restrict__ wp,
    const float* __restrict__ b2, const int* __restrict__ rois,
    float* __restrict__ part)
{
  const int t  = threadIdx.x;
  const int l  = t & 63, w = t >> 6;
  const int wm = w >> 1, wn = w & 1;
  const int bx = blockIdx.x & 3, by = blockIdx.x >> 2;
  const int b  = blockIdx.y;
  const int l15 = l & 15, l16 = l >> 4;

  __shared__ uint4 xs4[324 * 8];          // 18x18 rows x 128B = 41.5 KB
  __shared__ int   smax[NOBJ * 132];      // padded: bank = (4*id+oc)%32
  __shared__ int   ids_s[256];

  // ---- stage X tile: lane-contiguous LDS writes, swizzled global column ----
  const unsigned short* xb = xpad + (size_t)b * PADW * PADW * C1;
  for (int i = t; i < 2592; i += 512) {
    const int r = i >> 3, ps = i & 7;
    const int y = r / 18, x = r - y * 18;
    const int cl = ps ^ (r & 7);          // logical 16B-chunk within the row
    const int gy = by * 16 + y, gx = bx * 16 + x;
    xs4[i] = *(reinterpret_cast<const uint4*>(xb + ((size_t)gy * PADW + gx) * C1) + cl);
  }
  if (t < 256) {
    const int py = t >> 4, pxx = t & 15;
    ids_s[t] = rois[((size_t)b * IN + 2 * (by * 16 + py)) * IN + 2 * (bx * 16 + pxx)];
  }
  for (int i = t; i < NOBJ * 132; i += 512) smax[i] = 0;
  __syncthreads();

  f32x4 acc[4][4];
#pragma unroll
  for (int mf = 0; mf < 4; ++mf)
#pragma unroll
    for (int nf = 0; nf < 4; ++nf) acc[mf][nf] = (f32x4){0.f, 0.f, 0.f, 0.f};

  const char* xs_raw = reinterpret_cast<const char*>(xs4);

#pragma unroll
  for (int kr = 0; kr < 3; ++kr) {
#pragma unroll
    for (int kc = 0; kc < 3; ++kc) {
      const int tap = kr * 3 + kc;
#pragma unroll
      for (int k2 = 0; k2 < 2; ++k2) {
        bf16x8 a[4], bw[4];
#pragma unroll
        for (int mf = 0; mf < 4; ++mf) {
          const int m_loc = wm * 64 + mf * 16 + l15;
          const int py = m_loc >> 4, pxx = m_loc & 15;
          const int s = (py + kr) * 18 + (pxx + kc);
          const int c = (k2 * 4 + l16) ^ (s & 7);
          a[mf] = *reinterpret_cast<const bf16x8*>(xs_raw + s * 128 + c * 16);
        }
#pragma unroll
        for (int nf = 0; nf < 4; ++nf) {
          const int oc = wn * 64 + nf * 16 + l15;
          bw[nf] = *reinterpret_cast<const bf16x8*>(
              wp + ((size_t)tap * C2 + oc) * C1 + k2 * 32 + l16 * 8);
        }
#pragma unroll
        for (int mf = 0; mf < 4; ++mf)
#pragma unroll
          for (int nf = 0; nf < 4; ++nf)
            acc[mf][nf] = __builtin_amdgcn_mfma_f32_16x16x32_bf16(
                a[mf], bw[nf], acc[mf][nf], 0, 0, 0);
      }
    }
  }

  // ---- epilogue: bias + relu + LDS segment max ----
  float bias[4];
#pragma unroll
  for (int nf = 0; nf < 4; ++nf) bias[nf] = b2[wn * 64 + nf * 16 + l15];

#pragma unroll
  for (int mf = 0; mf < 4; ++mf) {
#pragma unroll
    for (int reg = 0; reg < 4; ++reg) {
      const int m_loc = wm * 64 + mf * 16 + l16 * 4 + reg;  // C/D row (m89)
      const int id = ids_s[m_loc];
#pragma unroll
      for (int nf = 0; nf < 4; ++nf) {
        const int oc = wn * 64 + nf * 16 + l15;             // C/D col
        const float val = fmaxf(acc[mf][nf][reg] + bias[nf], 0.f);
        atomicMax(&smax[id * 132 + oc], __float_as_int(val));
      }
    }
  }
  __syncthreads();

  // ---- drain to per-block partial (coalesced, no atomics) ----
  float* pb = part + ((size_t)b * 16 + blockIdx.x) * (NOBJ * C2);
  for (int i = t; i < NOBJ * C2; i += 512)
    pb[i] = __int_as_float(smax[(i >> 7) * 132 + (i & 127)]);
}

// ---------------------------------------------------------------------------
// K3: out[b][id][oc] = max over 16 spatial tiles of the per-block partials.
// Writes every output slot (absent id -> 0).
// ---------------------------------------------------------------------------
__global__ __launch_bounds__(256) void k3_reduce(
    const float* __restrict__ part, float* __restrict__ out)
{
  const int idx = blockIdx.x * 256 + threadIdx.x;   // < 32*4096
  const int b = idx >> 12, slot = idx & 4095;
  const float* p = part + (size_t)b * 16 * 4096 + slot;
  float m = 0.f;
#pragma unroll
  for (int tl = 0; tl < 16; ++tl) m = fmaxf(m, p[tl * 4096]);
  out[idx] = m;
}

extern "C" void kernel_launch(void* const* d_in, const int* in_sizes, int n_in,
                              void* d_out, int out_size, void* d_ws, size_t ws_size,
                              hipStream_t stream)
{
  (void)in_sizes; (void)n_in; (void)ws_size; (void)out_size;
  const float* images = (const float*)d_in[0];
  const int*   rois   = (const int*)d_in[1];
  const float* w1     = (const float*)d_in[2];
  const float* b1     = (const float*)d_in[3];
  const float* w2     = (const float*)d_in[4];
  const float* b2     = (const float*)d_in[5];

  const size_t xpad_bytes = (size_t)32 * PADW * PADW * C1 * 2;   // 17,842,176 B
  const size_t wpk_bytes  = (size_t)9 * C2 * C1 * 2;             // 147,456 B
  unsigned short* xpad = (unsigned short*)d_ws;
  unsigned short* wpk  = (unsigned short*)((char*)d_ws + xpad_bytes);
  float* part = (float*)((char*)d_ws + xpad_bytes + wpk_bytes);  // 512*16KB = 8.4 MB

  // zero xpad border (interior overwritten by k1)
  hipMemsetAsync(d_ws, 0, xpad_bytes, stream);

  hipLaunchKernelGGL(k0_pack_w, dim3(288), dim3(256), 0, stream, w2, wpk);

  dim3 blk1(64, 4, 1);
  dim3 g1(16, C1 / 16, 32);
  hipLaunchKernelGGL(k1_conv1_pool, g1, blk1, 0, stream, images, w1, b1, xpad);

  dim3 g2(16, 32, 1);
  hipLaunchKernelGGL(k2_mfma, g2, dim3(512), 0, stream, xpad, wpk, b2, rois, part);

  hipLaunchKernelGGL(k3_reduce, dim3(512), dim3(256), 0, stream, part, (float*)d_out);
}

// Round 5
// 95.783 us; speedup vs baseline: 1.9797x; 1.9797x over previous
//
#include <hip/hip_runtime.h>

#define IN 128
#define PD 64
#define C1 64
#define C2 128
#define ICC 12
#define NOBJ 32
#define PADW 66    // 64 + 1 halo each side (conv2 input)
#define IPW 130    // 128 + 1 halo each side (conv1 input)

typedef __attribute__((ext_vector_type(8))) short bf16x8;
typedef __attribute__((ext_vector_type(4))) float f32x4;

static __device__ __forceinline__ unsigned short f2bf(float f) {
  unsigned u = __float_as_uint(f);
  return (unsigned short)((u + 0x7FFFu + ((u >> 16) & 1u)) >> 16);  // RNE
}

// ---------------------------------------------------------------------------
// K0a: pack w2 (128,64,3,3) f32 -> wp2[tap][oc][ic] bf16  (147 KB)
// ---------------------------------------------------------------------------
__global__ __launch_bounds__(256) void k0_pack_w2(
    const float* __restrict__ w2, unsigned short* __restrict__ wp)
{
  int i = blockIdx.x * 256 + threadIdx.x;
  if (i < 9 * C2 * C1) {
    int tap = i / (C2 * C1);
    int rem = i - tap * (C2 * C1);
    int oc = rem >> 6, ic = rem & 63;
    wp[i] = f2bf(w2[(oc * C1 + ic) * 9 + tap]);
  }
}

// ---------------------------------------------------------------------------
// K0b: pack w1 (64,12,3,3) f32 -> wp1[tap(10)][oc(64)][ch(16)] bf16 (20 KB).
// ch >= 12 and tap 9 are zeros (K padding for the MFMA formulation).
// ---------------------------------------------------------------------------
__global__ __launch_bounds__(256) void k0_pack_w1(
    const float* __restrict__ w1, unsigned short* __restrict__ wp)
{
  int i = blockIdx.x * 256 + threadIdx.x;
  if (i < 10 * C1 * 16) {
    int tap = i >> 10;             // 64*16 = 1024 per tap
    int rem = i & 1023;
    int oc = rem >> 4, ch = rem & 15;
    float v = (tap < 9 && ch < ICC) ? w1[((size_t)oc * ICC + ch) * 9 + tap] : 0.f;
    wp[i] = f2bf(v);
  }
}

// ---------------------------------------------------------------------------
// Kimg: images (32,12,128,128) f32 -> ximg[b][130][130][16] bf16 = v/255,
// ch 12..15 zero, border rows/cols zero (pre-memset). Thread = one pixel.
// ---------------------------------------------------------------------------
__global__ __launch_bounds__(256) void k_img(
    const float* __restrict__ img, unsigned short* __restrict__ ximg)
{
  const int idx = blockIdx.x * 256 + threadIdx.x;   // 32*16384
  const int b = idx >> 14, pix = idx & 16383;
  const int y = pix >> 7, x = pix & 127;
  const float* ip = img + ((size_t)b * ICC << 14) + pix;
  unsigned int pk[8];
#pragma unroll
  for (int c = 0; c < ICC; c += 2) {
    unsigned short h0 = f2bf(ip[(size_t)c << 14] * (1.f / 255.f));
    unsigned short h1 = f2bf(ip[(size_t)(c + 1) << 14] * (1.f / 255.f));
    pk[c >> 1] = (unsigned int)h0 | ((unsigned int)h1 << 16);
  }
  pk[6] = 0; pk[7] = 0;
  unsigned short* dst = ximg + (((size_t)b * IPW + (y + 1)) * IPW + (x + 1)) * 16;
  reinterpret_cast<uint4*>(dst)[0] = make_uint4(pk[0], pk[1], pk[2], pk[3]);
  reinterpret_cast<uint4*>(dst)[1] = make_uint4(pk[4], pk[5], pk[6], pk[7]);
}

// ---------------------------------------------------------------------------
// K1: conv1 via MFMA (K = 2 taps x 16ch per k-step) + bias + ReLU + maxpool2x2
// fused in-register. Block: 512 thr (8 waves = 4M x 2N), 16x16 conv pixels,
// all 64 oc. LDS: 18x18x16ch bf16 tile (10.4 KB). 5 k-steps (9 taps + zero
// pad), 40 MFMA/wave. Pool: px pairs = reg pairs, row pairs = mf pairs ->
// all within-lane/within-wave; writes pooled bf16 directly to xpad NHWC.
// ---------------------------------------------------------------------------
__global__ __launch_bounds__(512) void k1_mfma(
    const unsigned short* __restrict__ ximg, const unsigned short* __restrict__ wp1,
    const float* __restrict__ b1, unsigned short* __restrict__ xpad)
{
  const int t = threadIdx.x;
  const int l = t & 63, w = t >> 6;
  const int wm = w >> 1, wn = w & 1;          // 4M x 2N
  const int bx = blockIdx.x & 7, by = blockIdx.x >> 3;
  const int b  = blockIdx.y;
  const int l15 = l & 15, l16 = l >> 4;

  __shared__ uint4 xs4[648];                  // 324 pix x 32B = 10368 B

  // ---- stage 18x18x16 input tile (contiguous writes, coalesced reads) ----
  const unsigned short* xb = ximg + (size_t)b * IPW * IPW * 16;
  for (int i = t; i < 648; i += 512) {
    const int pix = i >> 1, ck = i & 1;
    const int y = (pix * 57) >> 10;           // pix / 18
    const int x = pix - y * 18;
    const int gy = by * 16 + y, gx = bx * 16 + x;
    xs4[i] = *reinterpret_cast<const uint4*>(xb + ((size_t)(gy * IPW + gx) << 4) + (ck << 3));
  }
  __syncthreads();

  f32x4 acc[4][2];
#pragma unroll
  for (int mf = 0; mf < 4; ++mf)
#pragma unroll
    for (int nf = 0; nf < 2; ++nf) acc[mf][nf] = (f32x4){0.f, 0.f, 0.f, 0.f};

  const int ck = l16 & 1;
#pragma unroll
  for (int kp = 0; kp < 5; ++kp) {
    const int ta = 2 * kp, tb = 2 * kp + 1;   // tb == 9 on last step (zero W)
    const int tbA = (tb > 8) ? 8 : tb;        // valid LDS addr for pad step
    const int dya = ta / 3, dxa = ta % 3;
    const int dyb = tbA / 3, dxb = tbA % 3;
    const int dy = (l16 < 2) ? dya : dyb;     // per-lane tap select
    const int dx = (l16 < 2) ? dxa : dxb;
    const int tw = (l16 < 2) ? ta : tb;       // weight tap (9 -> zeros)

    bf16x8 a[4], bw[2];
#pragma unroll
    for (int mf = 0; mf < 4; ++mf) {
      const int row = wm * 4 + mf;
      a[mf] = *reinterpret_cast<const bf16x8*>(
          &xs4[((row + dy) * 18 + (l15 + dx)) * 2 + ck]);
    }
#pragma unroll
    for (int nf = 0; nf < 2; ++nf) {
      const int oc = wn * 32 + nf * 16 + l15;
      bw[nf] = *reinterpret_cast<const bf16x8*>(wp1 + ((tw * C1 + oc) * 16 + ck * 8));
    }
#pragma unroll
    for (int mf = 0; mf < 4; ++mf)
#pragma unroll
      for (int nf = 0; nf < 2; ++nf)
        acc[mf][nf] = __builtin_amdgcn_mfma_f32_16x16x32_bf16(
            a[mf], bw[nf], acc[mf][nf], 0, 0, 0);
  }

  // ---- fused 2x2 maxpool + bias + relu + bf16 store ----
  // D frag: conv px = l16*4 + reg, oc = l15, conv row = wm*4 + mf.
  float bias[2];
#pragma unroll
  for (int nf = 0; nf < 2; ++nf) bias[nf] = b1[wn * 32 + nf * 16 + l15];

#pragma unroll
  for (int q = 0; q < 2; ++q) {               // row pair (mf 2q, 2q+1)
    const int gy = by * 8 + wm * 2 + q;       // pooled row
    unsigned short* orow = xpad + (((size_t)b * PADW + (gy + 1)) * PADW + 1) * C1;
#pragma unroll
    for (int nf = 0; nf < 2; ++nf) {
      const int oc = wn * 32 + nf * 16 + l15;
      const f32x4 A0 = acc[2 * q][nf], A1 = acc[2 * q + 1][nf];
      const float p0 = fmaxf(fmaxf(A0[0], A0[1]), fmaxf(A1[0], A1[1]));
      const float p1 = fmaxf(fmaxf(A0[2], A0[3]), fmaxf(A1[2], A1[3]));
      const float v0 = fmaxf(p0 + bias[nf], 0.f);
      const float v1 = fmaxf(p1 + bias[nf], 0.f);
      const int gx0 = bx * 8 + l16 * 2;       // pooled cols (pair)
      orow[(size_t)gx0 * C1 + oc]       = f2bf(v0);
      orow[(size_t)(gx0 + 1) * C1 + oc] = f2bf(v1);
    }
  }
}

// ---------------------------------------------------------------------------
// K2: conv2 implicit GEMM via MFMA bf16 + bias/ReLU + per-block segment max.
// (unchanged from R3 — proven ~30us)
// ---------------------------------------------------------------------------
__global__ __launch_bounds__(512, 2) void k2_mfma(
    const unsigned short* __restrict__ xpad, const unsigned short* __restrict__ wp,
    const float* __restrict__ b2, const int* __restrict__ rois,
    float* __restrict__ part)
{
  const int t  = threadIdx.x;
  const int l  = t & 63, w = t >> 6;
  const int wm = w >> 1, wn = w & 1;
  const int bx = blockIdx.x & 3, by = blockIdx.x >> 2;
  const int b  = blockIdx.y;
  const int l15 = l & 15, l16 = l >> 4;

  __shared__ uint4 xs4[324 * 8];          // 18x18 rows x 128B = 41.5 KB
  __shared__ int   smax[NOBJ * 132];      // padded
  __shared__ int   ids_s[256];

  const unsigned short* xb = xpad + (size_t)b * PADW * PADW * C1;
  for (int i = t; i < 2592; i += 512) {
    const int r = i >> 3, ps = i & 7;
    const int y = r / 18, x = r - y * 18;
    const int cl = ps ^ (r & 7);
    const int gy = by * 16 + y, gx = bx * 16 + x;
    xs4[i] = *(reinterpret_cast<const uint4*>(xb + ((size_t)gy * PADW + gx) * C1) + cl);
  }
  if (t < 256) {
    const int py = t >> 4, pxx = t & 15;
    ids_s[t] = rois[((size_t)b * IN + 2 * (by * 16 + py)) * IN + 2 * (bx * 16 + pxx)];
  }
  for (int i = t; i < NOBJ * 132; i += 512) smax[i] = 0;
  __syncthreads();

  f32x4 acc[4][4];
#pragma unroll
  for (int mf = 0; mf < 4; ++mf)
#pragma unroll
    for (int nf = 0; nf < 4; ++nf) acc[mf][nf] = (f32x4){0.f, 0.f, 0.f, 0.f};

  const char* xs_raw = reinterpret_cast<const char*>(xs4);

#pragma unroll
  for (int kr = 0; kr < 3; ++kr) {
#pragma unroll
    for (int kc = 0; kc < 3; ++kc) {
      const int tap = kr * 3 + kc;
#pragma unroll
      for (int k2 = 0; k2 < 2; ++k2) {
        bf16x8 a[4], bw[4];
#pragma unroll
        for (int mf = 0; mf < 4; ++mf) {
          const int m_loc = wm * 64 + mf * 16 + l15;
          const int py = m_loc >> 4, pxx = m_loc & 15;
          const int s = (py + kr) * 18 + (pxx + kc);
          const int c = (k2 * 4 + l16) ^ (s & 7);
          a[mf] = *reinterpret_cast<const bf16x8*>(xs_raw + s * 128 + c * 16);
        }
#pragma unroll
        for (int nf = 0; nf < 4; ++nf) {
          const int oc = wn * 64 + nf * 16 + l15;
          bw[nf] = *reinterpret_cast<const bf16x8*>(
              wp + ((size_t)tap * C2 + oc) * C1 + k2 * 32 + l16 * 8);
        }
#pragma unroll
        for (int mf = 0; mf < 4; ++mf)
#pragma unroll
          for (int nf = 0; nf < 4; ++nf)
            acc[mf][nf] = __builtin_amdgcn_mfma_f32_16x16x32_bf16(
                a[mf], bw[nf], acc[mf][nf], 0, 0, 0);
      }
    }
  }

  float bias[4];
#pragma unroll
  for (int nf = 0; nf < 4; ++nf) bias[nf] = b2[wn * 64 + nf * 16 + l15];

#pragma unroll
  for (int mf = 0; mf < 4; ++mf) {
#pragma unroll
    for (int reg = 0; reg < 4; ++reg) {
      const int m_loc = wm * 64 + mf * 16 + l16 * 4 + reg;
      const int id = ids_s[m_loc];
#pragma unroll
      for (int nf = 0; nf < 4; ++nf) {
        const int oc = wn * 64 + nf * 16 + l15;
        const float val = fmaxf(acc[mf][nf][reg] + bias[nf], 0.f);
        atomicMax(&smax[id * 132 + oc], __float_as_int(val));
      }
    }
  }
  __syncthreads();

  float* pb = part + ((size_t)b * 16 + blockIdx.x) * (NOBJ * C2);
  for (int i = t; i < NOBJ * C2; i += 512)
    pb[i] = __int_as_float(smax[(i >> 7) * 132 + (i & 127)]);
}

// ---------------------------------------------------------------------------
// K3: out[b][id][oc] = max over 16 spatial tiles of the per-block partials.
// ---------------------------------------------------------------------------
__global__ __launch_bounds__(256) void k3_reduce(
    const float* __restrict__ part, float* __restrict__ out)
{
  const int idx = blockIdx.x * 256 + threadIdx.x;   // < 32*4096
  const int b = idx >> 12, slot = idx & 4095;
  const float* p = part + (size_t)b * 16 * 4096 + slot;
  float m = 0.f;
#pragma unroll
  for (int tl = 0; tl < 16; ++tl) m = fmaxf(m, p[tl * 4096]);
  out[idx] = m;
}

extern "C" void kernel_launch(void* const* d_in, const int* in_sizes, int n_in,
                              void* d_out, int out_size, void* d_ws, size_t ws_size,
                              hipStream_t stream)
{
  (void)in_sizes; (void)n_in; (void)ws_size; (void)out_size;
  const float* images = (const float*)d_in[0];
  const int*   rois   = (const int*)d_in[1];
  const float* w1     = (const float*)d_in[2];
  const float* b1     = (const float*)d_in[3];
  const float* w2     = (const float*)d_in[4];
  const float* b2     = (const float*)d_in[5];

  // ws layout (35.3 MB):
  //   [xpad 17,842,176][wp2 147,456][wp1 20,480][shared: ximg 17,305,600 | part 8,388,608]
  // ximg (k_img -> k1_mfma) and part (k2 -> k3) have disjoint lifetimes.
  const size_t xpad_bytes = (size_t)32 * PADW * PADW * C1 * 2;
  const size_t wp2_bytes  = (size_t)9 * C2 * C1 * 2;
  const size_t wp1_bytes  = (size_t)10 * C1 * 16 * 2;
  const size_t ximg_bytes = (size_t)32 * IPW * IPW * 16 * 2;

  unsigned short* xpad = (unsigned short*)d_ws;
  unsigned short* wp2  = (unsigned short*)((char*)d_ws + xpad_bytes);
  unsigned short* wp1  = (unsigned short*)((char*)d_ws + xpad_bytes + wp2_bytes);
  char* shared         = (char*)d_ws + xpad_bytes + wp2_bytes + wp1_bytes;
  unsigned short* ximg = (unsigned short*)shared;
  float* part          = (float*)shared;

  hipMemsetAsync(xpad, 0, xpad_bytes, stream);      // border zeros
  hipMemsetAsync(ximg, 0, ximg_bytes, stream);      // border + ch-pad zeros

  hipLaunchKernelGGL(k0_pack_w2, dim3(288), dim3(256), 0, stream, w2, wp2);
  hipLaunchKernelGGL(k0_pack_w1, dim3(40),  dim3(256), 0, stream, w1, wp1);
  hipLaunchKernelGGL(k_img, dim3(2048), dim3(256), 0, stream, images, ximg);

  hipLaunchKernelGGL(k1_mfma, dim3(64, 32), dim3(512), 0, stream,
                     ximg, wp1, b1, xpad);

  hipLaunchKernelGGL(k2_mfma, dim3(16, 32), dim3(512), 0, stream,
                     xpad, wp2, b2, rois, part);

  hipLaunchKernelGGL(k3_reduce, dim3(512), dim3(256), 0, stream,
                     part, (float*)d_out);
}